// Round 20
// baseline (261.710 us; speedup 1.0000x reference)
//
#include <hip/hip_runtime.h>
#include <hip/hip_fp16.h>

#define B 64
#define N 4096
#define M 128

__device__ __forceinline__ float2 cadd(float2 a, float2 b){ return make_float2(a.x+b.x, a.y+b.y); }
__device__ __forceinline__ float2 csub(float2 a, float2 b){ return make_float2(a.x-b.x, a.y-b.y); }
__device__ __forceinline__ float2 cmul(float2 a, float2 b){ return make_float2(a.x*b.x - a.y*b.y, a.x*b.y + a.y*b.x); }
__device__ __forceinline__ float2 mulnegi(float2 a){ return make_float2(a.y, -a.x); }
__device__ __forceinline__ float2 muli(float2 a)  { return make_float2(-a.y, a.x); }
__device__ __forceinline__ float2 cis(float ang){ float s, c; __sincosf(ang, &s, &c); return make_float2(c, s); }
__device__ __forceinline__ float2 h2f(__half2 h){ return __half22float2(h); }
__device__ __forceinline__ __half2 f2h(float2 v){ return __floats2half2_rn(v.x, v.y); }

// W64^d = cis(-2*pi*d/64), d = 0..7
__device__ __constant__ const float W64R[8] = {
    1.0f, 0.995184726672197f, 0.980785280403230f, 0.956940335732209f,
    0.923879532511287f, 0.881921264348355f, 0.831469612302545f, 0.773010453362737f };
__device__ __constant__ const float W64I[8] = {
    0.0f, -0.098017140329561f, -0.195090322016128f, -0.290284677254462f,
    -0.382683432365090f, -0.471396736825998f, -0.555570233019602f, -0.634393284163645f };

// forward DFT8 in place (W8 = e^{-i pi/4})
__device__ __forceinline__ void dft8(float2 t[8]) {
    float2 e0=cadd(t[0],t[4]), e1=csub(t[0],t[4]);
    float2 e2=cadd(t[2],t[6]), e3=csub(t[2],t[6]);
    float2 E0=cadd(e0,e2), E2=csub(e0,e2);
    float2 E1=cadd(e1,mulnegi(e3)), E3=cadd(e1,muli(e3));
    float2 o0=cadd(t[1],t[5]), o1=csub(t[1],t[5]);
    float2 o2=cadd(t[3],t[7]), o3=csub(t[3],t[7]);
    float2 O0=cadd(o0,o2), O2=csub(o0,o2);
    float2 O1=cadd(o1,mulnegi(o3)), O3=cadd(o1,muli(o3));
    const float C = 0.70710678118654752f;
    float2 w1O1 = make_float2(C*(O1.x+O1.y), C*(O1.y-O1.x));
    float2 w2O2 = mulnegi(O2);
    float2 w3O3 = make_float2(C*(O3.y-O3.x), -C*(O3.x+O3.y));
    t[0]=cadd(E0,O0);   t[4]=csub(E0,O0);
    t[1]=cadd(E1,w1O1); t[5]=csub(E1,w1O1);
    t[2]=cadd(E2,w2O2); t[6]=csub(E2,w2O2);
    t[3]=cadd(E3,w3O3); t[7]=csub(E3,w3O3);
}

// ==================== K1: FFT64 over n1 + global twiddle -> ws ====================
// thread = (b, n2, mc). ws[b][k1][n2][mc] half2 (67 MB). Stores: 256B contiguous.
__global__ __launch_bounds__(256, 4)
void fft_k1(const float* __restrict__ x, __half2* __restrict__ ws) {
    const int bid = blockIdx.x;
    const int b   = ((bid >> 7) << 3) | (bid & 7);   // bid%8 = b&7 -> co-XCD per batch
    const int blk = (bid >> 3) & 15;
    const int tid = threadIdx.x;
    const int mc  = tid & 63;
    const int n2  = (blk << 2) | (tid >> 6);

    const float* xb = x + (size_t)b * N * M + 2 * mc;

    __half2 pk[8][8];
    #pragma unroll
    for (int bb = 0; bb < 8; ++bb) {
        float2 t[8];
        #pragma unroll
        for (int a = 0; a < 8; ++a)
            t[a] = *(const float2*)(xb + (size_t)(64 * (8 * a + bb) + n2) * M);
        dft8(t);
        #pragma unroll
        for (int d = 0; d < 8; ++d) pk[bb][d] = f2h(t[d]);
    }
    const float ang = -6.2831853071795864f * (float)n2;
    const float2 wsc = cis(ang / 4096.0f);   // W4096^n2
    const float2 w8  = cis(ang / 512.0f);    // W4096^(8 n2)
    __half2* wsb = ws + ((size_t)b << 18) + ((size_t)n2 << 6) + mc;
    float2 pd = make_float2(1.f, 0.f);
    #pragma unroll
    for (int d = 0; d < 8; ++d) {
        const float2 wd = make_float2(W64R[d], W64I[d]);
        float2 t[8];
        t[0] = h2f(pk[0][d]);
        float2 w = wd;
        #pragma unroll
        for (int bb = 1; bb < 8; ++bb) { t[bb] = cmul(h2f(pk[bb][d]), w); w = cmul(w, wd); }
        dft8(t);
        float2 ac = pd;                      // W4096^{n2 * (8c+d)}
        #pragma unroll
        for (int c = 0; c < 8; ++c) {
            wsb[(size_t)(8 * c + d) << 12] = f2h(cmul(t[c], ac));
            ac = cmul(ac, w8);
        }
        pd = cmul(pd, wsc);
    }
}

// ==================== K2: FFT64 over n2 + Hermitian unpack -> out ====================
// thread = (b, mc, pair p): owns slices kA={0|p} and kB={32|64-p}; pairing is
// thread-local (partner index 63-k2 static under full unroll).
__global__ __launch_bounds__(256, 2)
void fft_k2(const __half2* __restrict__ ws, float* __restrict__ out) {
    __shared__ __half2 lda[64 * 256];   // [k2][tid] interleaved -> conflict-free, 64 KiB
    const int bid = blockIdx.x;
    const int b   = ((bid >> 6) << 3) | (bid & 7);
    const int mcg = (bid >> 3) & 7;
    const int tid = threadIdx.x;
    const int mc  = (mcg << 3) | (tid & 7);
    const int p   = tid >> 3;
    const int kA  = (p == 0) ? 0  : p;
    const int kB  = (p == 0) ? 32 : 64 - p;

    const __half2* wsb = ws + ((size_t)b << 18) + mc;

    __half2 pk[8][8];
    // ---- slice A -> LDS column ----
    #pragma unroll
    for (int bb = 0; bb < 8; ++bb) {
        float2 t[8];
        #pragma unroll
        for (int a = 0; a < 8; ++a)
            t[a] = h2f(wsb[((size_t)kA << 12) + ((8 * a + bb) << 6)]);
        dft8(t);
        #pragma unroll
        for (int d = 0; d < 8; ++d) pk[bb][d] = f2h(t[d]);
    }
    #pragma unroll
    for (int d = 0; d < 8; ++d) {
        const float2 wd = make_float2(W64R[d], W64I[d]);
        float2 t[8];
        t[0] = h2f(pk[0][d]);
        float2 w = wd;
        #pragma unroll
        for (int bb = 1; bb < 8; ++bb) { t[bb] = cmul(h2f(pk[bb][d]), w); w = cmul(w, wd); }
        dft8(t);
        #pragma unroll
        for (int c = 0; c < 8; ++c) lda[(8 * c + d) * 256 + tid] = f2h(t[c]);
    }
    // ---- slice B -> registers (static indices only) ----
    __half2 zb[64];
    #pragma unroll
    for (int bb = 0; bb < 8; ++bb) {
        float2 t[8];
        #pragma unroll
        for (int a = 0; a < 8; ++a)
            t[a] = h2f(wsb[((size_t)kB << 12) + ((8 * a + bb) << 6)]);
        dft8(t);
        #pragma unroll
        for (int d = 0; d < 8; ++d) pk[bb][d] = f2h(t[d]);
    }
    #pragma unroll
    for (int d = 0; d < 8; ++d) {
        const float2 wd = make_float2(W64R[d], W64I[d]);
        float2 t[8];
        t[0] = h2f(pk[0][d]);
        float2 w = wd;
        #pragma unroll
        for (int bb = 1; bb < 8; ++bb) { t[bb] = cmul(h2f(pk[bb][d]), w); w = cmul(w, wd); }
        dft8(t);
        #pragma unroll
        for (int c = 0; c < 8; ++c) zb[8 * c + d] = f2h(t[c]);
    }

    float* outRe = out + (size_t)b * N * M + 2 * mc;
    float* outIm = outRe + (size_t)B * N * M;

#define HSTORE(KROW, ZK, ZM) do {                                            \
        float2 _re = make_float2(0.5f * ((ZK).x + (ZM).x),                   \
                                 0.5f * ((ZK).y + (ZM).y));                  \
        float2 _im = make_float2(0.5f * ((ZK).y - (ZM).y),                   \
                                 0.5f * ((ZM).x - (ZK).x));                  \
        *(float2*)(outRe + (size_t)(KROW) * M) = _re;                        \
        *(float2*)(outIm + (size_t)(KROW) * M) = _im;                        \
    } while (0)

    if (p == 0) {
        #pragma unroll
        for (int k2 = 0; k2 < 64; ++k2) {
            // kA=0: self-paired, partner ZA[(64-k2)&63]
            float2 ZkA = h2f(lda[k2 * 256 + tid]);
            float2 ZmA = h2f(lda[(((64 - k2) & 63) * 256) + tid]);
            HSTORE(k2 << 6, ZkA, ZmA);
            // kB=32: self-paired, partner zb[63-k2]
            float2 ZkB = h2f(zb[k2]);
            float2 ZmB = h2f(zb[63 - k2]);
            HSTORE((k2 << 6) + 32, ZkB, ZmB);
        }
    } else {
        #pragma unroll
        for (int k2 = 0; k2 < 64; ++k2) {
            float2 ZkA = h2f(lda[k2 * 256 + tid]);
            float2 ZmA = h2f(zb[63 - k2]);
            HSTORE((k2 << 6) + kA, ZkA, ZmA);
            float2 ZkB = h2f(zb[k2]);
            float2 ZmB = h2f(lda[(63 - k2) * 256 + tid]);
            HSTORE((k2 << 6) + kB, ZkB, ZmB);
        }
    }
#undef HSTORE
}

// ==================== fallback: r17 single kernel (measured 122 us) ====================
__device__ __forceinline__ int lslot17(int k1, int n2, int mc) {
    return (k1 << 9) | ((n2 ^ (k1 & 7)) << 3) | mc;
}

__global__ __launch_bounds__(512, 2)
void fft_one17(const float* __restrict__ x, float* __restrict__ out) {
    extern __shared__ __half2 lz[];
    const int bid = blockIdx.x;
    const int b   = ((bid >> 6) << 3) | (bid & 7);
    const int mcg = (bid >> 3) & 7;
    const int tid = threadIdx.x;
    const int mc  = tid & 7;
    const int rp  = tid >> 3;
    const float* xb = x + (size_t)b * N * M + mcg * 16 + mc * 2;
    __half2 pk[8][8];
    #pragma unroll
    for (int bb = 0; bb < 8; ++bb) {
        float2 t[8];
        #pragma unroll
        for (int a = 0; a < 8; ++a)
            t[a] = *(const float2*)(xb + (size_t)(64*(8*a+bb) + rp) * M);
        dft8(t);
        #pragma unroll
        for (int d = 0; d < 8; ++d) pk[bb][d] = f2h(t[d]);
    }
    {
        const float2 ws_ = cis(-6.2831853071795864f * (float)rp / 4096.0f);
        const float2 w8  = cis(-6.2831853071795864f * (float)rp / 512.0f);
        float2 pd = make_float2(1.f, 0.f);
        #pragma unroll
        for (int d = 0; d < 8; ++d) {
            const float2 wd = make_float2(W64R[d], W64I[d]);
            float2 t[8];
            t[0] = h2f(pk[0][d]);
            float2 w = wd;
            #pragma unroll
            for (int bb = 1; bb < 8; ++bb) { t[bb] = cmul(h2f(pk[bb][d]), w); w = cmul(w, wd); }
            dft8(t);
            float2 ac = pd;
            #pragma unroll
            for (int c = 0; c < 8; ++c) {
                lz[lslot17(8*c+d, rp, mc)] = f2h(cmul(t[c], ac));
                ac = cmul(ac, w8);
            }
            pd = cmul(pd, ws_);
        }
    }
    __syncthreads();
    #pragma unroll
    for (int bb = 0; bb < 8; ++bb) {
        float2 t[8];
        #pragma unroll
        for (int a = 0; a < 8; ++a)
            t[a] = h2f(lz[lslot17(rp, 8*a+bb, mc)]);
        dft8(t);
        #pragma unroll
        for (int d = 0; d < 8; ++d) pk[bb][d] = f2h(t[d]);
    }
    #pragma unroll
    for (int d = 0; d < 8; ++d) {
        const float2 wd = make_float2(W64R[d], W64I[d]);
        float2 t[8];
        t[0] = h2f(pk[0][d]);
        float2 w = wd;
        #pragma unroll
        for (int bb = 1; bb < 8; ++bb) { t[bb] = cmul(h2f(pk[bb][d]), w); w = cmul(w, wd); }
        dft8(t);
        #pragma unroll
        for (int c = 0; c < 8; ++c)
            lz[lslot17(rp, 8*c+d, mc)] = f2h(t[c]);
    }
    __syncthreads();
    float* outRe = out + (size_t)b * N * M + mcg * 16 + mc * 2;
    float* outIm = outRe + (size_t)B * N * M;
    #pragma unroll 4
    for (int j = 0; j < 64; ++j) {
        int k   = (j << 6) | rp;
        int kk  = (N - k) & (N - 1);
        int k1p = kk & 63, k2p = kk >> 6;
        float2 Zk = h2f(lz[lslot17(rp,  j,   mc)]);
        float2 Zm = h2f(lz[lslot17(k1p, k2p, mc)]);
        float2 re = make_float2(0.5f * (Zk.x + Zm.x), 0.5f * (Zk.y + Zm.y));
        float2 im = make_float2(0.5f * (Zk.y - Zm.y), 0.5f * (Zm.x - Zk.x));
        *(float2*)(outRe + (size_t)k * M) = re;
        *(float2*)(outIm + (size_t)k * M) = im;
    }
}

extern "C" void kernel_launch(void* const* d_in, const int* in_sizes, int n_in,
                              void* d_out, int out_size, void* d_ws, size_t ws_size,
                              hipStream_t stream) {
    const float* x = (const float*)d_in[0];
    float* out = (float*)d_out;
    const size_t ws_needed = (size_t)B * 64 * 64 * 64 * sizeof(__half2);   // 67 MB
    if (ws_size >= ws_needed) {
        __half2* ws = (__half2*)d_ws;
        fft_k1<<<1024, 256, 0, stream>>>(x, ws);
        fft_k2<<<512, 256, 0, stream>>>(ws, out);
    } else {
        const int lds_bytes = 64 * 64 * 8 * (int)sizeof(__half2);   // 131072
        hipFuncSetAttribute((const void*)fft_one17,
                            hipFuncAttributeMaxDynamicSharedMemorySize, lds_bytes);
        fft_one17<<<512, 512, lds_bytes, stream>>>(x, out);
    }
}

// Round 21
// 129.710 us; speedup vs baseline: 2.0177x; 2.0177x over previous
//
#include <hip/hip_runtime.h>
#include <hip/hip_fp16.h>

#define B 64
#define N 4096
#define M 128

constexpr int T   = 512;    // 8 waves; 64 KiB LDS + 128 VGPR -> 2 blocks/CU
constexpr int NWG = 1024;   // 64 batches x 16 channel-groups (8 ch each)

__device__ __forceinline__ float2 cadd(float2 a, float2 b){ return make_float2(a.x+b.x, a.y+b.y); }
__device__ __forceinline__ float2 csub(float2 a, float2 b){ return make_float2(a.x-b.x, a.y-b.y); }
__device__ __forceinline__ float2 cmul(float2 a, float2 b){ return make_float2(a.x*b.x - a.y*b.y, a.x*b.y + a.y*b.x); }
__device__ __forceinline__ float2 mulnegi(float2 a){ return make_float2(a.y, -a.x); }
__device__ __forceinline__ float2 muli(float2 a)  { return make_float2(-a.y, a.x); }
__device__ __forceinline__ float2 cis(float ang){ float s, c; __sincosf(ang, &s, &c); return make_float2(c, s); }
__device__ __forceinline__ float2 h2f(__half2 h){ return __half22float2(h); }
__device__ __forceinline__ __half2 f2h(float2 v){ return __floats2half2_rn(v.x, v.y); }
__device__ __forceinline__ __half2 shxor4(__half2 v) {
    unsigned u = *(unsigned*)&v;
    unsigned r = (unsigned)__shfl_xor((int)u, 4, 64);
    return *(__half2*)&r;
}

// W64^d = cis(-2*pi*d/64), d = 0..7
__device__ __constant__ const float W64R[8] = {
    1.0f, 0.995184726672197f, 0.980785280403230f, 0.956940335732209f,
    0.923879532511287f, 0.881921264348355f, 0.831469612302545f, 0.773010453362737f };
__device__ __constant__ const float W64I[8] = {
    0.0f, -0.098017140329561f, -0.195090322016128f, -0.290284677254462f,
    -0.382683432365090f, -0.471396736825998f, -0.555570233019602f, -0.634393284163645f };

// forward DFT8 in place (W8 = e^{-i pi/4})
__device__ __forceinline__ void dft8(float2 t[8]) {
    float2 e0=cadd(t[0],t[4]), e1=csub(t[0],t[4]);
    float2 e2=cadd(t[2],t[6]), e3=csub(t[2],t[6]);
    float2 E0=cadd(e0,e2), E2=csub(e0,e2);
    float2 E1=cadd(e1,mulnegi(e3)), E3=cadd(e1,muli(e3));
    float2 o0=cadd(t[1],t[5]), o1=csub(t[1],t[5]);
    float2 o2=cadd(t[3],t[7]), o3=csub(t[3],t[7]);
    float2 O0=cadd(o0,o2), O2=csub(o0,o2);
    float2 O1=cadd(o1,mulnegi(o3)), O3=cadd(o1,muli(o3));
    const float C = 0.70710678118654752f;
    float2 w1O1 = make_float2(C*(O1.x+O1.y), C*(O1.y-O1.x));
    float2 w2O2 = mulnegi(O2);
    float2 w3O3 = make_float2(C*(O3.y-O3.x), -C*(O3.x+O3.y));
    t[0]=cadd(E0,O0);   t[4]=csub(E0,O0);
    t[1]=cadd(E1,w1O1); t[5]=csub(E1,w1O1);
    t[2]=cadd(E2,w2O2); t[6]=csub(E2,w2O2);
    t[3]=cadd(E3,w3O3); t[7]=csub(E3,w3O3);
}

// LDS half2 slot, 4 planes: XOR swizzle n2^(k1&7); all phases <=2-way (free)
__device__ __forceinline__ int lslot(int k1, int n2, int mc) {
    return (k1 << 8) | ((n2 ^ (k1 & 7)) << 2) | mc;
}

__global__ __launch_bounds__(T, 2)   // 2 blocks/CU min -> VGPR cap 128 (no spill)
void fft_one(const float* __restrict__ x, float* __restrict__ out) {
    extern __shared__ __half2 lz[];   // [64 k1][64 n2 sw][4 mc] = 64 KiB

    // bid%8 = b&7 -> all 16 channel-groups of a batch on one XCD
    const int bid = blockIdx.x;
    const int b   = ((bid >> 7) << 3) | (bid & 7);
    const int mcg = (bid >> 3) & 15;
    const int tid = threadIdx.x;
    const int mc  = tid & 3;           // plane (packed channel pair)
    const int s   = (tid >> 2) & 1;    // column-half selector (lane bit 2)
    const int rp  = tid >> 3;          // phase A: n2 ; phase B: k1 ; unpack: r

    const float* xb = x + (size_t)b * N * M + mcg * 8 + mc * 2;

    __half2 pk[4][8];    // my 4 columns' DFT8 outputs (static idx only)
    __half2 rcv[4][4];   // partner's values for my d' range

    // ======== phase A: FFT64 over n1 of column n2=rp (columns split by s) ====
    #pragma unroll
    for (int cc = 0; cc < 4; ++cc) {
        const int bb = 4 * s + cc;
        float2 t[8];
        #pragma unroll
        for (int a = 0; a < 8; ++a)
            t[a] = *(const float2*)(xb + (size_t)(64 * (8 * a + bb) + rp) * M);
        dft8(t);
        #pragma unroll
        for (int d = 0; d < 8; ++d) pk[cc][d] = f2h(t[d]);
    }
    // exchange: receive partner's pk[cc][4s+dd] (their bb = 4(1-s)+cc)
    #pragma unroll
    for (int cc = 0; cc < 4; ++cc)
        #pragma unroll
        for (int dd = 0; dd < 4; ++dd) {
            __half2 lo = pk[cc][dd], hi = pk[cc][4 + dd];
            rcv[cc][dd] = shxor4(s ? lo : hi);   // send pk[cc][4(1-s)+dd]
        }
    // pass 2: for my d' = 4s+dd: X[8c+d'] = DFT8_bb(W64^{bb d'} U_bb[d'])[c],
    // then global twiddle W4096^{rp(8c+d')} and LDS write.
    {
        const float ang = -6.2831853071795864f * (float)rp;
        const float2 ws  = cis(ang / 4096.0f);   // W4096^rp
        const float2 ws4 = cis(ang / 1024.0f);   // ws^4
        const float2 w8  = cis(ang / 512.0f);    // ws^8
        float2 pd = s ? ws4 : make_float2(1.f, 0.f);   // ws^{4s}
        #pragma unroll
        for (int dd = 0; dd < 4; ++dd) {
            float2 w1a = make_float2(W64R[dd],     W64I[dd]);
            float2 w1b = make_float2(W64R[4 + dd], W64I[4 + dd]);
            float2 w1 = s ? w1b : w1a;           // W64^{d'}
            float2 t[8];
            #pragma unroll
            for (int cc = 0; cc < 4; ++cc) {
                float2 own = h2f(s ? pk[cc][4 + dd] : pk[cc][dd]); // pk[cc][4s+dd]
                float2 rv  = h2f(rcv[cc][dd]);
                t[cc]     = s ? rv  : own;       // slot bb = cc   (own iff s==0)
                t[4 + cc] = s ? own : rv;        // slot bb = 4+cc
            }
            {
                float2 w = w1;
                #pragma unroll
                for (int bb = 1; bb < 8; ++bb) { t[bb] = cmul(t[bb], w); w = cmul(w, w1); }
            }
            dft8(t);
            const int dp = 4 * s + dd;
            float2 ac = pd;                      // ws^{d'}
            #pragma unroll
            for (int c = 0; c < 8; ++c) {
                lz[lslot(8 * c + dp, rp, mc)] = f2h(cmul(t[c], ac));
                ac = cmul(ac, w8);
            }
            pd = cmul(pd, ws);
        }
    }
    __syncthreads();

    // ======== phase B: FFT64 over n2 of own slice k1=rp (race-free by mod-8) ==
    #pragma unroll
    for (int cc = 0; cc < 4; ++cc) {
        const int bb = 4 * s + cc;
        float2 t[8];
        #pragma unroll
        for (int a = 0; a < 8; ++a)
            t[a] = h2f(lz[lslot(rp, 8 * a + bb, mc)]);
        dft8(t);
        #pragma unroll
        for (int d = 0; d < 8; ++d) pk[cc][d] = f2h(t[d]);
    }
    #pragma unroll
    for (int cc = 0; cc < 4; ++cc)
        #pragma unroll
        for (int dd = 0; dd < 4; ++dd) {
            __half2 lo = pk[cc][dd], hi = pk[cc][4 + dd];
            rcv[cc][dd] = shxor4(s ? lo : hi);
        }
    #pragma unroll
    for (int dd = 0; dd < 4; ++dd) {
        float2 w1a = make_float2(W64R[dd],     W64I[dd]);
        float2 w1b = make_float2(W64R[4 + dd], W64I[4 + dd]);
        float2 w1 = s ? w1b : w1a;
        float2 t[8];
        #pragma unroll
        for (int cc = 0; cc < 4; ++cc) {
            float2 own = h2f(s ? pk[cc][4 + dd] : pk[cc][dd]);
            float2 rv  = h2f(rcv[cc][dd]);
            t[cc]     = s ? rv  : own;
            t[4 + cc] = s ? own : rv;
        }
        {
            float2 w = w1;
            #pragma unroll
            for (int bb = 1; bb < 8; ++bb) { t[bb] = cmul(t[bb], w); w = cmul(w, w1); }
        }
        dft8(t);
        const int dp = 4 * s + dd;
        #pragma unroll
        for (int c = 0; c < 8; ++c)
            lz[lslot(rp, 8 * c + dp, mc)] = f2h(t[c]);   // Z[k2=8c+d']
    }
    __syncthreads();

    // ======== Hermitian unpack + stores (rows k = 64j + rp, j split by s) ====
    float* outRe = out + (size_t)b * N * M + mcg * 8 + mc * 2;
    float* outIm = outRe + (size_t)B * N * M;
    #pragma unroll 4
    for (int jj = 0; jj < 32; ++jj) {
        int j  = 32 * s + jj;
        int k  = (j << 6) | rp;
        int kk = (N - k) & (N - 1);
        int k1p = kk & 63, k2p = kk >> 6;
        float2 Zk = h2f(lz[lslot(rp,  j,   mc)]);
        float2 Zm = h2f(lz[lslot(k1p, k2p, mc)]);
        float2 re = make_float2(0.5f * (Zk.x + Zm.x), 0.5f * (Zk.y + Zm.y));
        float2 im = make_float2(0.5f * (Zk.y - Zm.y), 0.5f * (Zm.x - Zk.x));
        *(float2*)(outRe + (size_t)k * M) = re;
        *(float2*)(outIm + (size_t)k * M) = im;
    }
}

extern "C" void kernel_launch(void* const* d_in, const int* in_sizes, int n_in,
                              void* d_out, int out_size, void* d_ws, size_t ws_size,
                              hipStream_t stream) {
    const float* x = (const float*)d_in[0];
    float* out = (float*)d_out;
    const int lds_bytes = 64 * 64 * 4 * (int)sizeof(__half2);   // 65536
    hipFuncSetAttribute((const void*)fft_one,
                        hipFuncAttributeMaxDynamicSharedMemorySize, lds_bytes);
    fft_one<<<NWG, T, lds_bytes, stream>>>(x, out);
}

// Round 22
// 123.901 us; speedup vs baseline: 2.1123x; 1.0469x over previous
//
#include <hip/hip_runtime.h>
#include <hip/hip_fp16.h>

#define B 64
#define N 4096
#define M 128

constexpr int T   = 512;    // 8 waves; 128 KiB LDS -> 1 block/CU; VGPR cap 128
constexpr int NWG = 512;    // 64 batches x 8 channel-groups (16 ch each)

__device__ __forceinline__ float2 cadd(float2 a, float2 b){ return make_float2(a.x+b.x, a.y+b.y); }
__device__ __forceinline__ float2 csub(float2 a, float2 b){ return make_float2(a.x-b.x, a.y-b.y); }
__device__ __forceinline__ float2 cmul(float2 a, float2 b){ return make_float2(a.x*b.x - a.y*b.y, a.x*b.y + a.y*b.x); }
__device__ __forceinline__ float2 mulnegi(float2 a){ return make_float2(a.y, -a.x); }
__device__ __forceinline__ float2 muli(float2 a)  { return make_float2(-a.y, a.x); }
__device__ __forceinline__ float2 cis(float ang){ float s, c; __sincosf(ang, &s, &c); return make_float2(c, s); }
__device__ __forceinline__ float2 h2f(__half2 h){ return __half22float2(h); }
__device__ __forceinline__ __half2 f2h(float2 v){ return __floats2half2_rn(v.x, v.y); }

// W64^d = cis(-2*pi*d/64), d = 0..7
__device__ __constant__ const float W64R[8] = {
    1.0f, 0.995184726672197f, 0.980785280403230f, 0.956940335732209f,
    0.923879532511287f, 0.881921264348355f, 0.831469612302545f, 0.773010453362737f };
__device__ __constant__ const float W64I[8] = {
    0.0f, -0.098017140329561f, -0.195090322016128f, -0.290284677254462f,
    -0.382683432365090f, -0.471396736825998f, -0.555570233019602f, -0.634393284163645f };

// forward DFT8 in place (W8 = e^{-i pi/4})
__device__ __forceinline__ void dft8(float2 t[8]) {
    float2 e0=cadd(t[0],t[4]), e1=csub(t[0],t[4]);
    float2 e2=cadd(t[2],t[6]), e3=csub(t[2],t[6]);
    float2 E0=cadd(e0,e2), E2=csub(e0,e2);
    float2 E1=cadd(e1,mulnegi(e3)), E3=cadd(e1,muli(e3));
    float2 o0=cadd(t[1],t[5]), o1=csub(t[1],t[5]);
    float2 o2=cadd(t[3],t[7]), o3=csub(t[3],t[7]);
    float2 O0=cadd(o0,o2), O2=csub(o0,o2);
    float2 O1=cadd(o1,mulnegi(o3)), O3=cadd(o1,muli(o3));
    const float C = 0.70710678118654752f;
    float2 w1O1 = make_float2(C*(O1.x+O1.y), C*(O1.y-O1.x));
    float2 w2O2 = mulnegi(O2);
    float2 w3O3 = make_float2(C*(O3.y-O3.x), -C*(O3.x+O3.y));
    t[0]=cadd(E0,O0);   t[4]=csub(E0,O0);
    t[1]=cadd(E1,w1O1); t[5]=csub(E1,w1O1);
    t[2]=cadd(E2,w2O2); t[6]=csub(E2,w2O2);
    t[3]=cadd(E3,w3O3); t[7]=csub(E3,w3O3);
}

// LDS half2 slot: XOR swizzle n2^(k1&7) => every phase <=2-way (free)
__device__ __forceinline__ int lslot(int k1, int n2, int mc) {
    return (k1 << 9) | ((n2 ^ (k1 & 7)) << 3) | mc;
}

__global__ __launch_bounds__(T, 2)
void fft_one(const float* __restrict__ x, float* __restrict__ out) {
    extern __shared__ __half2 lz[];   // [k1][n2 sw][mc] = 64*64*8 half2 = 128 KiB

    // bid%8 = b&7 -> all 8 channel-groups of a batch on one XCD
    const int bid = blockIdx.x;
    const int b   = ((bid >> 6) << 3) | (bid & 7);
    const int mcg = (bid >> 3) & 7;
    const int tid = threadIdx.x;
    const int mc  = tid & 7;        // packed channel pair within group
    const int rp  = tid >> 3;       // phase A: n2 ; phase B: k1

    const float* xb = x + (size_t)b * N * M + mcg * 16 + mc * 2;

    __half2 pk[8][8];   // fp16-packed pass-1 intermediates (64 VGPRs, static idx)

    // ======== phase A: FFT64 over n1 of column n2=rp ========
    #pragma unroll
    for (int bb = 0; bb < 8; ++bb) {
        float2 t[8];
        #pragma unroll
        for (int a = 0; a < 8; ++a)
            t[a] = *(const float2*)(xb + (size_t)(64*(8*a+bb) + rp) * M);
        dft8(t);
        #pragma unroll
        for (int d = 0; d < 8; ++d) pk[bb][d] = f2h(t[d]);
    }
    {
        const float2 ws_ = cis(-6.2831853071795864f * (float)rp / 4096.0f);
        const float2 w8  = cis(-6.2831853071795864f * (float)rp / 512.0f);
        float2 pd = make_float2(1.f, 0.f);
        #pragma unroll
        for (int d = 0; d < 8; ++d) {
            const float2 wd = make_float2(W64R[d], W64I[d]);
            float2 t[8];
            t[0] = h2f(pk[0][d]);
            float2 w = wd;
            #pragma unroll
            for (int bb = 1; bb < 8; ++bb) { t[bb] = cmul(h2f(pk[bb][d]), w); w = cmul(w, wd); }
            dft8(t);
            float2 ac = pd;
            #pragma unroll
            for (int c = 0; c < 8; ++c) {
                lz[lslot(8*c+d, rp, mc)] = f2h(cmul(t[c], ac));
                ac = cmul(ac, w8);
            }
            pd = cmul(pd, ws_);
        }
    }
    __syncthreads();

    // ======== phase B: FFT64 over n2 of own slice k1=rp ========
    #pragma unroll
    for (int bb = 0; bb < 8; ++bb) {
        float2 t[8];
        #pragma unroll
        for (int a = 0; a < 8; ++a)
            t[a] = h2f(lz[lslot(rp, 8*a+bb, mc)]);
        dft8(t);
        #pragma unroll
        for (int d = 0; d < 8; ++d) pk[bb][d] = f2h(t[d]);
    }
    #pragma unroll
    for (int d = 0; d < 8; ++d) {
        const float2 wd = make_float2(W64R[d], W64I[d]);
        float2 t[8];
        t[0] = h2f(pk[0][d]);
        float2 w = wd;
        #pragma unroll
        for (int bb = 1; bb < 8; ++bb) { t[bb] = cmul(h2f(pk[bb][d]), w); w = cmul(w, wd); }
        dft8(t);
        #pragma unroll
        for (int c = 0; c < 8; ++c)
            lz[lslot(rp, 8*c+d, mc)] = f2h(t[c]);   // Z[k2=8c+d], self-owned slice
    }
    __syncthreads();

    // ======== paired Hermitian unpack: each (Zk,Zm) LDS pair read ONCE ========
    float* outRe = out + (size_t)b * N * M + mcg * 16 + mc * 2;
    float* outIm = outRe + (size_t)B * N * M;

#define HSTORE(KROW, ZK, ZM) do {                                            \
        float2 _re = make_float2(0.5f * ((ZK).x + (ZM).x),                   \
                                 0.5f * ((ZK).y + (ZM).y));                  \
        float2 _im = make_float2(0.5f * ((ZK).y - (ZM).y),                   \
                                 0.5f * ((ZM).x - (ZK).x));                  \
        *(float2*)(outRe + (size_t)(KROW) * M) = _re;                        \
        *(float2*)(outIm + (size_t)(KROW) * M) = _im;                        \
    } while (0)

    if (rp >= 1 && rp <= 31) {
        const int rq = 64 - rp;             // partner slice (owned jointly)
        #pragma unroll 4
        for (int j = 0; j < 64; ++j) {
            float2 Zk = h2f(lz[lslot(rp, j,      mc)]);   // Z[64j + rp]
            float2 Zm = h2f(lz[lslot(rq, 63 - j, mc)]);   // Z[N - (64j+rp)]
            HSTORE((j << 6) | rp, Zk, Zm);
            HSTORE(((63 - j) << 6) | rq, Zm, Zk);
        }
    } else if (rp == 0) {
        #pragma unroll 4
        for (int j = 0; j <= 32; ++j) {
            int jm = (64 - j) & 63;
            float2 Zk = h2f(lz[lslot(0, j,  mc)]);
            float2 Zm = h2f(lz[lslot(0, jm, mc)]);
            HSTORE(j << 6, Zk, Zm);
            if (j >= 1 && j <= 31) HSTORE(jm << 6, Zm, Zk);
        }
    } else if (rp == 32) {
        #pragma unroll 4
        for (int j = 0; j < 32; ++j) {
            float2 Zk = h2f(lz[lslot(32, j,      mc)]);
            float2 Zm = h2f(lz[lslot(32, 63 - j, mc)]);
            HSTORE((j << 6) | 32, Zk, Zm);
            HSTORE(((63 - j) << 6) | 32, Zm, Zk);
        }
    }
#undef HSTORE
}

extern "C" void kernel_launch(void* const* d_in, const int* in_sizes, int n_in,
                              void* d_out, int out_size, void* d_ws, size_t ws_size,
                              hipStream_t stream) {
    const float* x = (const float*)d_in[0];
    float* out = (float*)d_out;
    const int lds_bytes = 64 * 64 * 8 * (int)sizeof(__half2);   // 131072
    hipFuncSetAttribute((const void*)fft_one,
                        hipFuncAttributeMaxDynamicSharedMemorySize, lds_bytes);
    fft_one<<<NWG, T, lds_bytes, stream>>>(x, out);
}